// Round 7
// baseline (563.007 us; speedup 1.0000x reference)
//
#include <hip/hip_runtime.h>

typedef float f32x4 __attribute__((ext_vector_type(4)));
typedef short bfrag __attribute__((ext_vector_type(8)));
typedef short s16x8 __attribute__((ext_vector_type(8)));
typedef unsigned short u16;

__device__ __forceinline__ u16 f2bf(float f) {
  union { float f; unsigned u; } x; x.f = f;
  unsigned r = x.u + 0x7fffu + ((x.u >> 16) & 1u);
  return (u16)(r >> 16);
}
__device__ __forceinline__ float bf2f(u16 v) {
  union { unsigned u; float f; } x; x.u = ((unsigned)v) << 16;
  return x.f;
}

__device__ __forceinline__ void g2l16(const void* g, void* l) {
  void* gnc = const_cast<void*>(g);
  __builtin_amdgcn_global_load_lds((__attribute__((address_space(1))) void*)gnc,
                                   (__attribute__((address_space(3))) void*)l, 16, 0, 0);
}

// asm ds_read_b128: invisible to compiler aliasing vs global_load_lds -> no auto vmcnt(0)
__device__ __forceinline__ bfrag ldsr(const u16* p) {
  bfrag r;
  asm volatile("ds_read_b128 %0, %1"
               : "=v"(r)
               : "v"((__attribute__((address_space(3))) const u16*)p));
  return r;
}

__device__ __forceinline__ f32x4 mfma16(bfrag a, bfrag b, f32x4 c) {
  asm volatile("v_mfma_f32_16x16x32_bf16 %0, %1, %2, %0" : "+v"(c) : "v"(a), "v"(b));
  return c;
}

__device__ __forceinline__ float wred_sum(float s) {
  #pragma unroll
  for (int o = 32; o; o >>= 1) s += __shfl_xor(s, o);
  return s;
}

__device__ __forceinline__ float gelu_f(float v) {
  return 0.5f * v * (1.f + erff(v * 0.70710678118f));
}

// ---------------- fused f32 -> bf16 convert ----------------
struct CvtArgs {
  const float* s[14];
  u16* d[14];
  int eb[14];
};

__global__ __launch_bounds__(256) void cvt_all(CvtArgs a) {
  const int blk = blockIdx.x;
  int base = 0;
  const float* sp = a.s[0];
  u16* dp = a.d[0];
  #pragma unroll
  for (int i = 0; i < 13; ++i) {
    if (blk >= a.eb[i]) { base = a.eb[i]; sp = a.s[i + 1]; dp = a.d[i + 1]; }
  }
  const size_t gi = ((size_t)(blk - base) * 256 + threadIdx.x) * 4;
  float4 f = *(const float4*)(sp + gi);
  ushort4 o;
  o.x = f2bf(f.x); o.y = f2bf(f.y); o.z = f2bf(f.z); o.w = f2bf(f.w);
  *(ushort4*)(dp + gi) = o;
}

// ---------------- bias concat ----------------
__global__ __launch_bounds__(512) void biascat_k(
    const float* __restrict__ bkp, const float* __restrict__ bvp,
    const float* __restrict__ bqp, const float* __restrict__ bkd,
    const float* __restrict__ bvd, float* __restrict__ bp3,
    float* __restrict__ bd2) {
  int t = threadIdx.x;
  bp3[t] = bkp[t];
  bp3[512 + t] = bvp[t];
  bp3[1024 + t] = bqp[t];
  bd2[t] = bkd[t];
  bd2[512 + t] = bvd[t];
}

// ---------------- uncertainty gates ----------------
__device__ __forceinline__ float softplus_s(float x) {
  return fmaxf(x, 0.f) + log1pf(expf(-fabsf(x)));
}

__global__ __launch_bounds__(256) void gate_k(
    const float* __restrict__ hd, const float* __restrict__ hp,
    const float* __restrict__ wd, const float* __restrict__ bd,
    const float* __restrict__ wp, const float* __restrict__ bp,
    float* __restrict__ lgd, float* __restrict__ lgp, int mdTok) {
  const int lane = threadIdx.x & 63, wv = threadIdx.x >> 6;
  size_t tok = (size_t)blockIdx.x * 4 + wv;
  const float* h; const float* w4; const float* b4; float* lg;
  if (tok < (size_t)mdTok) { h = hd; w4 = wd; b4 = bd; lg = lgd; }
  else { h = hp; w4 = wp; b4 = bp; lg = lgp; tok -= mdTok; }
  const float* x = h + tok * 512;
  float s0 = 0.f, s1 = 0.f, s2 = 0.f, s3 = 0.f;
  #pragma unroll
  for (int i = 0; i < 8; ++i) {
    int c = (i << 6) + lane;
    float xv = x[c];
    s0 += xv * w4[c];
    s1 += xv * w4[512 + c];
    s2 += xv * w4[1024 + c];
    s3 += xv * w4[1536 + c];
  }
  s0 = wred_sum(s0); s1 = wred_sum(s1); s2 = wred_sum(s2); s3 = wred_sum(s3);
  if (lane == 0) {
    float mu = s0 + b4[0];
    float va = softplus_s(s1 + b4[1]) + 1e-6f;
    float al = softplus_s(s2 + b4[2]) + 1.f + 1e-6f;
    float be = softplus_s(s3 + b4[3]) + 1e-6f;
    float se2 = be / (va * (al - 1.f));
    float g = (1.f / (1.f + expf(-mu))) * expf(-se2);
    g = fminf(fmaxf(g, 1e-3f), 1.f);
    lg[tok] = logf(g + 1e-9f);
  }
}

// ---------------- residual(bf16) + LayerNorm ----------------
template <int OUT>
__global__ __launch_bounds__(256) void ln_k(const u16* __restrict__ res,
                                            const u16* __restrict__ y,
                                            const float* __restrict__ sc,
                                            const float* __restrict__ bi,
                                            void* __restrict__ outv) {
  const int lane = threadIdx.x & 63, w = threadIdx.x >> 6;
  const size_t row = (size_t)blockIdx.x * 4 + w;
  const int c0 = lane * 8;
  float v[8];
  s16x8 yv = *(const s16x8*)(y + row * 512 + c0);
  s16x8 rv = *(const s16x8*)(res + row * 512 + c0);
  float s = 0.f;
  #pragma unroll
  for (int i = 0; i < 8; ++i) {
    v[i] = bf2f((u16)rv[i]) + bf2f((u16)yv[i]);
    s += v[i];
  }
  s = wred_sum(s);
  float m = s * (1.f / 512.f);
  float s2 = 0.f;
  #pragma unroll
  for (int i = 0; i < 8; ++i) { float d = v[i] - m; s2 += d * d; }
  s2 = wred_sum(s2);
  float inv = rsqrtf(s2 * (1.f / 512.f) + 1e-5f);
  float4 sc0 = *(const float4*)(sc + c0), sc1 = *(const float4*)(sc + c0 + 4);
  float4 bi0 = *(const float4*)(bi + c0), bi1 = *(const float4*)(bi + c0 + 4);
  float scv[8] = {sc0.x, sc0.y, sc0.z, sc0.w, sc1.x, sc1.y, sc1.z, sc1.w};
  float biv[8] = {bi0.x, bi0.y, bi0.z, bi0.w, bi1.x, bi1.y, bi1.z, bi1.w};
  float o[8];
  #pragma unroll
  for (int i = 0; i < 8; ++i) o[i] = (v[i] - m) * inv * scv[i] + biv[i];
  if constexpr (OUT == 0) {
    float* of = (float*)outv + row * 512 + c0;
    *(float4*)of = float4{o[0], o[1], o[2], o[3]};
    *(float4*)(of + 4) = float4{o[4], o[5], o[6], o[7]};
  } else {
    s16x8 ov;
    #pragma unroll
    for (int i = 0; i < 8; ++i) ov[i] = (short)f2bf(o[i]);
    *(s16x8*)((u16*)outv + row * 512 + c0) = ov;
  }
}

// ---------------- fused flash cross-attention (Out may alias Q: per-block disjoint) ----------------
template <int KT>
__global__ __launch_bounds__(256) void flash_k(
    const u16* __restrict__ Q, const u16* __restrict__ Kv,
    const u16* __restrict__ Vt, const float* __restrict__ logg,
    const int* __restrict__ mask, u16* __restrict__ Out,
    int Lq, int Lk, float scale) {
  __shared__ __align__(16) u16 Kl[KT * 64];
  __shared__ __align__(16) u16 Vl[64 * KT];
  __shared__ __align__(16) u16 Pl[64 * (KT + 8)];
  const int tid = threadIdx.x;
  const int lane = tid & 63, wv = tid >> 6;
  const int lr = lane & 15, lg4 = lane >> 4;
  const int bh = blockIdx.z;
  const int b = bh >> 3, h = bh & 7;
  const int q0 = blockIdx.x * 64;

  bfrag af[2];
  {
    const u16* qrow = Q + (size_t)(b * Lq + q0 + wv * 16 + lr) * 512 + h * 64;
    af[0] = *(const bfrag*)(qrow + lg4 * 8);
    af[1] = *(const bfrag*)(qrow + 32 + lg4 * 8);
  }
  float mreg[4] = {-3e38f, -3e38f, -3e38f, -3e38f};
  float lreg[4] = {0.f, 0.f, 0.f, 0.f};
  f32x4 Oa[4] = {};
  const float* lgb = logg + (size_t)b * Lk;
  const int* mkb = mask + (size_t)b * Lk;

  const int NKT = Lk / KT;
  for (int t = 0; t < NKT; ++t) {
    const int k0 = t * KT;
    __syncthreads();
    {
      const char* kb = (const char*)(Kv + (size_t)(b * Lk + k0) * 512 + h * 64);
      #pragma unroll
      for (int r = 0; r < KT / 32; ++r) {
        int o = r * 4096 + tid * 16;
        int rr = o >> 7, cd = (o >> 4) & 7;
        int cs = cd ^ (rr & 7);
        g2l16(kb + (size_t)rr * 1024 + cs * 16, (char*)Kl + o);
      }
      const char* vb = (const char*)(Vt + (size_t)bh * 64 * Lk + k0);
      #pragma unroll
      for (int r = 0; r < KT / 32; ++r) {
        int o = r * 4096 + tid * 16;
        int rr = o >> 8, cd = (o >> 4) & 15;
        int cs = (cd & 8) | ((cd & 7) ^ (rr & 7));
        g2l16(vb + (size_t)rr * (Lk * 2) + cs * 16, (char*)Vl + o);
      }
    }
    __syncthreads();

    f32x4 sa[KT / 16];
    #pragma unroll
    for (int n = 0; n < KT / 16; ++n) {
      sa[n] = f32x4{0.f, 0.f, 0.f, 0.f};
      int row = n * 16 + lr;
      #pragma unroll
      for (int ks = 0; ks < 2; ++ks) {
        bfrag kf = *(const bfrag*)(Kl + row * 64 + (((ks * 4 + lg4) ^ (row & 7)) * 8));
        sa[n] = mfma16(af[ks], kf, sa[n]);
      }
    }
    asm volatile("s_nop 7\n\ts_nop 7");

    float pv[KT / 16][4];
    float nm[4] = {-3e38f, -3e38f, -3e38f, -3e38f};
    #pragma unroll
    for (int n = 0; n < KT / 16; ++n) {
      int kk = k0 + n * 16 + lr;
      float lgv = lgb[kk];
      int mkv = mkb[kk];
      #pragma unroll
      for (int e = 0; e < 4; ++e) {
        float tv = mkv ? fmaf(sa[n][e], scale, lgv) : -1e9f;
        pv[n][e] = tv;
        nm[e] = fmaxf(nm[e], tv);
      }
    }
    float fac[4], rs[4];
    #pragma unroll
    for (int e = 0; e < 4; ++e) {
      nm[e] = fmaxf(nm[e], __shfl_xor(nm[e], 1));
      nm[e] = fmaxf(nm[e], __shfl_xor(nm[e], 2));
      nm[e] = fmaxf(nm[e], __shfl_xor(nm[e], 4));
      nm[e] = fmaxf(nm[e], __shfl_xor(nm[e], 8));
      nm[e] = fmaxf(nm[e], mreg[e]);
      fac[e] = __expf(mreg[e] - nm[e]);
      mreg[e] = nm[e];
      rs[e] = 0.f;
    }
    #pragma unroll
    for (int n = 0; n < KT / 16; ++n)
      #pragma unroll
      for (int e = 0; e < 4; ++e) {
        float p = __expf(pv[n][e] - nm[e]);
        pv[n][e] = p;
        rs[e] += p;
      }
    #pragma unroll
    for (int e = 0; e < 4; ++e) {
      rs[e] += __shfl_xor(rs[e], 1);
      rs[e] += __shfl_xor(rs[e], 2);
      rs[e] += __shfl_xor(rs[e], 4);
      rs[e] += __shfl_xor(rs[e], 8);
      lreg[e] = lreg[e] * fac[e] + rs[e];
    }
    #pragma unroll
    for (int n2 = 0; n2 < 4; ++n2)
      #pragma unroll
      for (int e = 0; e < 4; ++e) Oa[n2][e] *= fac[e];

    {
      int prow = wv * 16 + lg4 * 4;
      #pragma unroll
      for (int n = 0; n < KT / 16; ++n)
        #pragma unroll
        for (int e = 0; e < 4; ++e)
          Pl[(prow + e) * (KT + 8) + n * 16 + lr] = f2bf(pv[n][e]);
    }
    #pragma unroll
    for (int ks = 0; ks < KT / 32; ++ks) {
      bfrag pf = *(const bfrag*)(Pl + (wv * 16 + lr) * (KT + 8) + (ks * 4 + lg4) * 8);
      #pragma unroll
      for (int n2 = 0; n2 < 4; ++n2) {
        int vrow = n2 * 16 + lr;
        int ch = ks * 4 + lg4;
        int chs = (ch & 8) | ((ch & 7) ^ (vrow & 7));
        bfrag vf = *(const bfrag*)(Vl + vrow * KT + chs * 8);
        Oa[n2] = mfma16(pf, vf, Oa[n2]);
      }
    }
  }
  asm volatile("s_nop 7\n\ts_nop 7");

  float inv[4];
  #pragma unroll
  for (int e = 0; e < 4; ++e) inv[e] = 1.f / lreg[e];
  u16* ob = Out + (size_t)(b * Lq + q0 + wv * 16 + lg4 * 4) * 512 + h * 64;
  #pragma unroll
  for (int n2 = 0; n2 < 4; ++n2)
    #pragma unroll
    for (int e = 0; e < 4; ++e)
      ob[(size_t)e * 512 + n2 * 16 + lr] = f2bf(Oa[n2][e] * inv[e]);
}

// ---------------- m97-structure 128x128 MFMA GEMM ----------------
// EPI: 1=bf16, 2=gelu->bf16, 5=concat (c<512 -> C; else V^T -> C2)
template <int FM, int FN, int EPI>
__global__ __launch_bounds__(256) void gemm_k(
    const u16* __restrict__ A, const u16* __restrict__ W,
    const float* __restrict__ bias, void* __restrict__ C, void* __restrict__ C2,
    int K, int lda, int ldw, int ldc, int NB, int TR) {
  constexpr int BM = 2 * FM * 16;
  constexpr int BN = 2 * FN * 16;
  __shared__ __align__(16) u16 Al[BM * 64];
  __shared__ __align__(16) u16 Wl[BN * 64];
  const int tid = threadIdx.x;
  const int qq = gridDim.x >> 3;
  const int wg = (blockIdx.x & 7) * qq + (blockIdx.x >> 3);
  const int bx = wg % NB, by = wg / NB;
  const int row0 = by * BM, col0 = bx * BN;
  const int lane = tid & 63, wv = tid >> 6;
  const int wr = wv >> 1, wc = wv & 1;
  const int rowW = wr * FM * 16, colW = wc * FN * 16;
  const int lr = lane & 15, lg4 = lane >> 4;

  const u16* aSrc[BM / 32];
  const u16* wSrc[BN / 32];
  int aDst[BM / 32], wDst[BN / 32];
  #pragma unroll
  for (int r = 0; r < BM / 32; ++r) {
    int o = r * 4096 + tid * 16;
    int arow = o >> 7, cd = (o >> 4) & 7, cs = cd ^ (arow & 7);
    aSrc[r] = A + (size_t)(row0 + arow) * lda + cs * 8;
    aDst[r] = o;
  }
  #pragma unroll
  for (int r = 0; r < BN / 32; ++r) {
    int o = r * 4096 + tid * 16;
    int wrow = o >> 7, cd = (o >> 4) & 7, cs = cd ^ (wrow & 7);
    wSrc[r] = W + (size_t)(col0 + wrow) * ldw + cs * 8;
    wDst[r] = o;
  }
  int aOff[FM][2], wOff[FN][2];
  #pragma unroll
  for (int m = 0; m < FM; ++m) {
    int rowi = rowW + m * 16 + lr;
    #pragma unroll
    for (int ks = 0; ks < 2; ++ks)
      aOff[m][ks] = rowi * 64 + (((ks * 4 + lg4) ^ (rowi & 7)) * 8);
  }
  #pragma unroll
  for (int n = 0; n < FN; ++n) {
    int rowi = colW + n * 16 + lr;
    #pragma unroll
    for (int ks = 0; ks < 2; ++ks)
      wOff[n][ks] = rowi * 64 + (((ks * 4 + lg4) ^ (rowi & 7)) * 8);
  }

  f32x4 acc[FM][FN] = {};

  for (int k0 = 0; k0 < K; k0 += 64) {
    #pragma unroll
    for (int r = 0; r < BM / 32; ++r) g2l16(aSrc[r] + k0, (char*)Al + aDst[r]);
    #pragma unroll
    for (int r = 0; r < BN / 32; ++r) g2l16(wSrc[r] + k0, (char*)Wl + wDst[r]);
    __syncthreads();
    #pragma unroll
    for (int ks = 0; ks < 2; ++ks) {
      bfrag af[FM], wf[FN];
      #pragma unroll
      for (int m = 0; m < FM; ++m) af[m] = *(const bfrag*)(Al + aOff[m][ks]);
      #pragma unroll
      for (int n = 0; n < FN; ++n) wf[n] = *(const bfrag*)(Wl + wOff[n][ks]);
      #pragma unroll
      for (int m = 0; m < FM; ++m)
        #pragma unroll
        for (int n = 0; n < FN; ++n) acc[m][n] = mfma16(af[m], wf[n], acc[m][n]);
    }
    __syncthreads();
  }
  asm volatile("s_nop 7\n\ts_nop 7\n\ts_nop 7");

  #pragma unroll
  for (int m = 0; m < FM; ++m) {
    #pragma unroll
    for (int n = 0; n < FN; ++n) {
      int rb = row0 + rowW + m * 16 + lg4 * 4;
      int c = col0 + colW + n * 16 + lr;
      float bv = bias[c];
      if constexpr (EPI == 1) {
        u16* Cu = (u16*)C;
        #pragma unroll
        for (int e = 0; e < 4; ++e)
          Cu[(size_t)(rb + e) * ldc + c] = f2bf(acc[m][n][e] + bv);
      } else if constexpr (EPI == 2) {
        u16* Cu = (u16*)C;
        #pragma unroll
        for (int e = 0; e < 4; ++e)
          Cu[(size_t)(rb + e) * ldc + c] = f2bf(gelu_f(acc[m][n][e] + bv));
      } else {  // EPI == 5: c<512 -> C standard; else V^T -> C2
        if (c < 512) {
          u16* Cu = (u16*)C;
          #pragma unroll
          for (int e = 0; e < 4; ++e)
            Cu[(size_t)(rb + e) * ldc + c] = f2bf(acc[m][n][e] + bv);
        } else {
          u16* Cu = (u16*)C2;
          int cl = c - 512;
          int b2 = rb / TR, j0 = rb - b2 * TR;
          int h2 = cl >> 6, dd = cl & 63;
          ushort4 pk;
          pk.x = f2bf(acc[m][n][0] + bv);
          pk.y = f2bf(acc[m][n][1] + bv);
          pk.z = f2bf(acc[m][n][2] + bv);
          pk.w = f2bf(acc[m][n][3] + bv);
          *(ushort4*)&Cu[(((size_t)b2 * 8 + h2) * 64 + dd) * TR + j0] = pk;
        }
      }
    }
  }
}

// ---------------- 8-phase 256x256 MFMA GEMM, asm-ds_read version ----------------
#define GBAR asm volatile("s_barrier" ::: "memory")
#define LGK0 asm volatile("s_waitcnt lgkmcnt(0)" ::: "memory"); __builtin_amdgcn_sched_barrier(0)
template <int EPI>
__global__ __launch_bounds__(512, 1) void gemm8_k(
    const u16* __restrict__ A, const u16* __restrict__ W,
    const float* __restrict__ bias, void* __restrict__ C, void* __restrict__ C2,
    void* __restrict__ C3, int K, int lda, int ldw, int ldc, int NB, int TR) {
  __shared__ __align__(16) u16 Ab[2][2][128 * 64];
  __shared__ __align__(16) u16 Bb[2][2][128 * 64];
  const int tid = threadIdx.x;
  const int qq = gridDim.x >> 3;
  const int wg = (blockIdx.x & 7) * qq + (blockIdx.x >> 3);
  const int bx = wg % NB, by = wg / NB;
  const int row0 = by * 256, col0 = bx * 256;
  const int lane = tid & 63, wv = tid >> 6;
  const int wr = wv >> 2, wc = wv & 3;
  const int lr = lane & 15, lg4 = lane >> 4;
  const int NT = K >> 6;

  const int srow = tid >> 3;
  const int scs = (tid & 7) ^ (srow & 7);
  const u16* aS[2][2];
  const u16* wS[2][2];
  #pragma unroll
  for (int h = 0; h < 2; ++h)
    #pragma unroll
    for (int i = 0; i < 2; ++i) {
      int r = i * 64 + srow;
      aS[h][i] = A + (size_t)(row0 + h * 128 + r) * lda + scs * 8;
      wS[h][i] = W + (size_t)(col0 + h * 128 + r) * ldw + scs * 8;
    }
  const int dstoff = tid * 16;

  auto stA = [&](int buf, int h, int tt) {
    if (tt < NT) {
      char* d = (char*)&Ab[buf][h][0];
      g2l16(aS[h][0] + tt * 64, d + dstoff);
      g2l16(aS[h][1] + tt * 64, d + 8192 + dstoff);
    }
  };
  auto stB = [&](int buf, int h, int tt) {
    if (tt < NT) {
      char* d = (char*)&Bb[buf][h][0];
      g2l16(wS[h][0] + tt * 64, d + dstoff);
      g2l16(wS[h][1] + tt * 64, d + 8192 + dstoff);
    }
  };

  const u16* Abase[2] = {&Ab[0][wr][0], &Ab[1][wr][0]};
  const u16* Bbase[2] = {&Bb[0][wc >> 1][0], &Bb[1][wc >> 1][0]};
  int cko[2];
  #pragma unroll
  for (int kk = 0; kk < 2; ++kk) cko[kk] = ((kk * 4 + lg4) ^ (lr & 7)) * 8;
  const int brow0 = (wc & 1) * 64;

  f32x4 acc[8][4] = {};
  bfrag ar[4][2], b0r[2][2], b1r[2][2];

#define LDA8(buf, qm)                                                     \
  {                                                                       \
    const u16* _b = Abase[buf];                                           \
    _Pragma("unroll") for (int m = 0; m < 4; ++m) {                       \
      int ro = (((qm) * 4 + m) * 16 + lr) * 64;                           \
      ar[m][0] = ldsr(_b + ro + cko[0]);                                  \
      ar[m][1] = ldsr(_b + ro + cko[1]);                                  \
    }                                                                     \
  }
#define LDB8(buf, qn, br)                                                 \
  {                                                                       \
    const u16* _b = Bbase[buf];                                           \
    _Pragma("unroll") for (int n = 0; n < 2; ++n) {                       \
      int ro = (brow0 + ((qn) * 2 + n) * 16 + lr) * 64;                   \
      br[n][0] = ldsr(_b + ro + cko[0]);                                  \
      br[n][1] = ldsr(_b + ro + cko[1]);                                  \
    }                                                                     \
  }
#define MM8(qm, qn, br)                                                   \
  {                                                                       \
    __builtin_amdgcn_s_setprio(1);                                        \
    _Pragma("unroll") for (int m = 0; m < 4; ++m)                         \
        _Pragma("unroll") for (int n = 0; n < 2; ++n) {                   \
      acc[(qm) * 4 + m][(qn) * 2 + n] =                                   \
          mfma16(ar[m][0], br[n][0], acc[(qm) * 4 + m][(qn) * 2 + n]);    \
      acc[(qm) * 4 + m][(qn) * 2 + n] =                                   \
          mfma16(ar[m][1], br[n][1], acc[(qm) * 4 + m][(qn) * 2 + n]);    \
    }                                                                     \
    __builtin_amdgcn_s_setprio(0);                                        \
  }

  // prologue: tile0 full -> buf0 (oldest 8 loads), tile1 3 halves -> buf1
  stB(0, 0, 0); stB(0, 1, 0); stA(0, 0, 0); stA(0, 1, 0);
  stB(1, 0, 1); stB(1, 1, 1); stA(1, 0, 1);
  asm volatile("s_waitcnt vmcnt(6)" ::: "memory");
  GBAR;

  const int NI = NT >> 1;
  for (int j = 0; j < NI; ++j) {
    const int t2 = 2 * j + 2, t3 = 2 * j + 3;
    const bool last = (j == NI - 1);
    LDA8(0, 0); LDB8(0, 0, b0r); stA(1, 1, 2 * j + 1);
    GBAR; LGK0; MM8(0, 0, b0r); GBAR;
    LDB8(0, 1, b1r); stB(0, 0, t2);
    GBAR; LGK0; MM8(0, 1, b1r); GBAR;
    LDA8(0, 1); stB(0, 1, t2);
    GBAR; LGK0; MM8(1, 1, b1r); GBAR;
    stA(0, 0, t2);
    if (last) asm volatile("s_waitcnt vmcnt(0)" ::: "memory");
    else      asm volatile("s_waitcnt vmcnt(6)" ::: "memory");
    GBAR; MM8(1, 0, b0r); GBAR;
    LDA8(1, 0); LDB8(1, 0, b0r); stA(0, 1, t2);
    GBAR; LGK0; MM8(0, 0, b0r); GBAR;
    LDB8(1, 1, b1r); stB(1, 0, t3);
    GBAR; LGK0; MM8(0, 1, b1r); GBAR;
    LDA8(1, 1); stB(1, 1, t3);
    GBAR; LGK0; MM8(1, 1, b1r); GBAR;
    stA(1, 0, t3);
    if (!last) asm volatile("s_waitcnt vmcnt(6)" ::: "memory");
    GBAR; MM8(1, 0, b0r); GBAR;
  }
  asm volatile("s_nop 7\n\ts_nop 7\n\ts_nop 7");

  #pragma unroll
  for (int mf = 0; mf < 8; ++mf) {
    #pragma unroll
    for (int nf = 0; nf < 4; ++nf) {
      int rb = row0 + wr * 128 + mf * 16 + lg4 * 4;
      int c = col0 + wc * 64 + nf * 16 + lr;
      float bv = bias[c];
      if constexpr (EPI == 2) {
        u16* Cu = (u16*)C;
        #pragma unroll
        for (int e = 0; e < 4; ++e)
          Cu[(size_t)(rb + e) * ldc + c] = f2bf(gelu_f(acc[mf][nf][e] + bv));
      } else {  // EPI == 4: kvq concat routing
        if (c < 512) {
          u16* Cu = (u16*)C;
          #pragma unroll
          for (int e = 0; e < 4; ++e)
            Cu[(size_t)(rb + e) * 512 + c] = f2bf(acc[mf][nf][e] + bv);
        } else if (c < 1024) {
          u16* Cu = (u16*)C2;
          int cl = c - 512;
          int b2 = rb / TR, j0 = rb - b2 * TR;
          int h2 = cl >> 6, dd = cl & 63;
          ushort4 pk;
          pk.x = f2bf(acc[mf][nf][0] + bv);
          pk.y = f2bf(acc[mf][nf][1] + bv);
          pk.z = f2bf(acc[mf][nf][2] + bv);
          pk.w = f2bf(acc[mf][nf][3] + bv);
          *(ushort4*)&Cu[(((size_t)b2 * 8 + h2) * 64 + dd) * TR + j0] = pk;
        } else {
          u16* Cu = (u16*)C3;
          int cl = c - 1024;
          #pragma unroll
          for (int e = 0; e < 4; ++e)
            Cu[(size_t)(rb + e) * 512 + cl] = f2bf(acc[mf][nf][e] + bv);
        }
      }
    }
  }
#undef LDA8
#undef LDB8
#undef MM8
}

// =============================== host ===============================
extern "C" void kernel_launch(void* const* d_in, const int* in_sizes, int n_in,
                              void* d_out, int out_size, void* d_ws, size_t ws_size,
                              hipStream_t stream) {
  const float* h_d = (const float*)d_in[0];
  const float* h_p = (const float*)d_in[1];
  const float* gd_w = (const float*)d_in[2];
  const float* gd_b = (const float*)d_in[3];
  const float* gp_w = (const float*)d_in[4];
  const float* gp_b = (const float*)d_in[5];
  const float* wqd_w = (const float*)d_in[6];  const float* wqd_b = (const float*)d_in[7];
  const float* wkp_w = (const float*)d_in[8];  const float* wkp_b = (const float*)d_in[9];
  const float* wvp_w = (const float*)d_in[10]; const float* wvp_b = (const float*)d_in[11];
  const float* wqp_w = (const float*)d_in[12]; const float* wqp_b = (const float*)d_in[13];
  const float* wkd_w = (const float*)d_in[14]; const float* wkd_b = (const float*)d_in[15];
  const float* wvd_w = (const float*)d_in[16]; const float* wvd_b = (const float*)d_in[17];
  const float* od_w = (const float*)d_in[18];  const float* od_b = (const float*)d_in[19];
  const float* op_w = (const float*)d_in[20];  const float* op_b = (const float*)d_in[21];
  const float* fd1_w = (const float*)d_in[22]; const float* fd1_b = (const float*)d_in[23];
  const float* fd2_w = (const float*)d_in[24]; const float* fd2_b = (const float*)d_in[25];
  const float* fp1_w = (const float*)d_in[26]; const float* fp1_b = (const float*)d_in[27];
  const float* fp2_w = (const float*)d_in[28]; const float* fp2_b = (const float*)d_in[29];
  const float* nd1_s = (const float*)d_in[30]; const float* nd1_b = (const float*)d_in[31];
  const float* nd2_s = (const float*)d_in[32]; const float* nd2_b = (const float*)d_in[33];
  const float* np1_s = (const float*)d_in[34]; const float* np1_b = (const float*)d_in[35];
  const float* np2_s = (const float*)d_in[36]; const float* np2_b = (const float*)d_in[37];
  const int* mask_d = (const int*)d_in[38];
  const int* mask_p = (const int*)d_in[39];

  constexpr int B = 16, Ld = 256, Lp = 1024, D = 512, H = 8, F = 2048;
  constexpr int Md = B * Ld;   // 4096
  constexpr int Mp = B * Lp;   // 16384
  constexpr int BH = B * H;    // 128

  char* ws = (char*)d_ws;
  size_t off = 0;
  auto alloc = [&](size_t bytes) {
    size_t o = off;
    off += (bytes + 255) & ~(size_t)255;
    return o;
  };
  auto a16 = [&](size_t els) { return (u16*)(ws + alloc(els * 2)); };
  auto a32 = [&](size_t els) { return (float*)(ws + alloc(els * 4)); };

  u16* w_qd = a16((size_t)D * D);
  u16* w_kp = a16((size_t)D * D);  // w_kp|w_vp|w_qp contiguous (1536 x 512)
  u16* w_vp = a16((size_t)D * D);
  u16* w_qp = a16((size_t)D * D);
  u16* w_kd = a16((size_t)D * D);  // w_kd|w_vd contiguous (1024 x 512)
  u16* w_vd = a16((size_t)D * D);
  u16* w_od = a16((size_t)D * D);
  u16* w_op = a16((size_t)D * D);
  u16* w_fd1 = a16((size_t)F * D);
  u16* w_fd2 = a16((size_t)F * D);
  u16* w_fp1 = a16((size_t)F * D);
  u16* w_fp2 = a16((size_t)F * D);

  u16* hd16 = a16((size_t)Md * D);     // h_d bf16 (pristine; LN1 residual)
  u16* hd2_16 = a16((size_t)Md * D);   // h_d'
  u16* hp16 = a16((size_t)Mp * D);     // h_p bf16 (pristine) -> h_p' after LN2 (in-place)
  u16* qd16 = a16((size_t)Md * D);     // qd -> attn1 out (in-place) -> kd
  u16* kp16 = a16((size_t)Mp * D);     // kp
  u16* qp16 = a16((size_t)Mp * D);     // qp -> attn2 out (in-place)
  u16* vt16 = a16((size_t)Mp * D);     // vp^T -> vd^T
  u16* obuf16 = a16((size_t)Mp * D);   // o-proj / ffn2 outputs
  u16* t16 = a16((size_t)Mp * F);      // ffn hidden
  float* logg_d = a32(Md);
  float* logg_p = a32(Mp);
  float* bp3 = a32(1536);
  float* bd2 = a32(1024);

  // --- fused conversions ---
  {
    CvtArgs a;
    const float* src[14] = {h_d, h_p, wqd_w, wkp_w, wvp_w, wqp_w, wkd_w,
                            wvd_w, od_w, op_w, fd1_w, fd2_w, fp1_w, fp2_w};
    u16* dst[14] = {hd16, hp16, w_qd, w_kp, w_vp, w_qp, w_kd,
                    w_vd, w_od, w_op, w_fd1, w_fd2, w_fp1, w_fp2};
    const int nelem[14] = {Md * D, Mp * D, D * D, D * D, D * D, D * D, D * D,
                           D * D, D * D, D * D, F * D, F * D, F * D, F * D};
    int pfx = 0;
    for (int i = 0; i < 14; ++i) {
      a.s[i] = src[i];
      a.d[i] = dst[i];
      pfx += nelem[i] / 1024;
      a.eb[i] = pfx;
    }
    cvt_all<<<pfx, 256, 0, stream>>>(a);
  }
  biascat_k<<<1, 512, 0, stream>>>(wkp_b, wvp_b, wqp_b, wkd_b, wvd_b, bp3, bd2);

  // --- gates (ORIGINAL fp32 inputs) ---
  gate_k<<<(Md + Mp) / 4, 256, 0, stream>>>(h_d, h_p, gd_w, gd_b, gp_w, gp_b,
                                            logg_d, logg_p, Md);

  // --- fused kp|vp|qp projection, 8-phase 256^2 ---
  gemm8_k<4><<<(Mp / 256) * (1536 / 256), 512, 0, stream>>>(
      hp16, w_kp, bp3, kp16, vt16, qp16, D, D, D, 0, 1536 / 256, Lp);

  // --- qd projection ---
  gemm_k<4, 4, 1><<<(Md / 128) * (D / 128), 256, 0, stream>>>(
      hd16, w_qd, wqd_b, qd16, nullptr, D, D, D, D, D / 128, 0);

  // --- attn1 (out in-place over qd16) ---
  flash_k<128><<<dim3(Ld / 64, 1, BH), 256, 0, stream>>>(
      qd16, kp16, vt16, logg_p, mask_p, qd16, Ld, Lp, 0.125f);

  // --- o-proj + LN1 -> h_d' ---
  gemm_k<4, 4, 1><<<(Md / 128) * (D / 128), 256, 0, stream>>>(
      qd16, w_od, od_b, obuf16, nullptr, D, D, D, D, D / 128, 0);
  ln_k<1><<<Md / 4, 256, 0, stream>>>(hd16, obuf16, nd1_s, nd1_b, hd2_16);

  // --- kd|vd concat projection (from UPDATED drug) ---
  gemm_k<4, 4, 5><<<(Md / 128) * (1024 / 128), 256, 0, stream>>>(
      hd2_16, w_kd, bd2, qd16, vt16, D, D, D, D, 1024 / 128, Ld);

  // --- attn2 (out in-place over qp16) ---
  flash_k<128><<<dim3(Lp / 64, 1, BH), 256, 0, stream>>>(
      qp16, qd16, vt16, logg_d, mask_d, qp16, Lp, Ld, 0.125f);

  // --- o-proj + LN2 -> h_p' (in-place into hp16) ---
  gemm_k<4, 4, 1><<<(Mp / 128) * (D / 128), 256, 0, stream>>>(
      qp16, w_op, op_b, obuf16, nullptr, D, D, D, D, D / 128, 0);
  ln_k<1><<<Mp / 4, 256, 0, stream>>>(hp16, obuf16, np1_s, np1_b, hp16);

  // --- FFN drug + final LN -> d_out[0 : Md*D] ---
  gemm_k<4, 4, 2><<<(Md / 128) * (F / 128), 256, 0, stream>>>(
      hd2_16, w_fd1, fd1_b, t16, nullptr, D, D, D, F, F / 128, 0);
  gemm_k<4, 4, 1><<<(Md / 128) * (D / 128), 256, 0, stream>>>(
      t16, w_fd2, fd2_b, obuf16, nullptr, F, F, F, D, D / 128, 0);
  ln_k<0><<<Md / 4, 256, 0, stream>>>(hd2_16, obuf16, nd2_s, nd2_b, (float*)d_out);

  // --- FFN protein + final LN -> d_out[Md*D : ] ---
  gemm8_k<2><<<(Mp / 256) * (F / 256), 512, 0, stream>>>(
      hp16, w_fp1, fp1_b, t16, nullptr, nullptr, D, D, D, F, F / 256, 0);
  gemm_k<4, 4, 1><<<(Mp / 128) * (D / 128), 256, 0, stream>>>(
      t16, w_fp2, fp2_b, obuf16, nullptr, F, F, F, D, D / 128, 0);
  ln_k<0><<<Mp / 4, 256, 0, stream>>>(hp16, obuf16, np2_s, np2_b,
                                      (float*)d_out + (size_t)Md * D);
}

// Round 8
// 396.536 us; speedup vs baseline: 1.4198x; 1.4198x over previous
//
#include <hip/hip_runtime.h>

typedef float f32x4 __attribute__((ext_vector_type(4)));
typedef short bfrag __attribute__((ext_vector_type(8)));
typedef short s16x8 __attribute__((ext_vector_type(8)));
typedef unsigned short u16;

__device__ __forceinline__ u16 f2bf(float f) {
  union { float f; unsigned u; } x; x.f = f;
  unsigned r = x.u + 0x7fffu + ((x.u >> 16) & 1u);
  return (u16)(r >> 16);
}
__device__ __forceinline__ float bf2f(u16 v) {
  union { unsigned u; float f; } x; x.u = ((unsigned)v) << 16;
  return x.f;
}

__device__ __forceinline__ void g2l16(const void* g, void* l) {
  void* gnc = const_cast<void*>(g);
  __builtin_amdgcn_global_load_lds((__attribute__((address_space(1))) void*)gnc,
                                   (__attribute__((address_space(3))) void*)l, 16, 0, 0);
}

__device__ __forceinline__ f32x4 mfma16(bfrag a, bfrag b, f32x4 c) {
  asm volatile("v_mfma_f32_16x16x32_bf16 %0, %1, %2, %0" : "+v"(c) : "v"(a), "v"(b));
  return c;
}

__device__ __forceinline__ float wred_sum(float s) {
  #pragma unroll
  for (int o = 32; o; o >>= 1) s += __shfl_xor(s, o);
  return s;
}

__device__ __forceinline__ float gelu_f(float v) {
  return 0.5f * v * (1.f + erff(v * 0.70710678118f));
}

// ---------------- fused f32 -> bf16 convert ----------------
struct CvtArgs {
  const float* s[14];
  u16* d[14];
  int eb[14];
};

__global__ __launch_bounds__(256) void cvt_all(CvtArgs a) {
  const int blk = blockIdx.x;
  int base = 0;
  const float* sp = a.s[0];
  u16* dp = a.d[0];
  #pragma unroll
  for (int i = 0; i < 13; ++i) {
    if (blk >= a.eb[i]) { base = a.eb[i]; sp = a.s[i + 1]; dp = a.d[i + 1]; }
  }
  const size_t gi = ((size_t)(blk - base) * 256 + threadIdx.x) * 4;
  float4 f = *(const float4*)(sp + gi);
  ushort4 o;
  o.x = f2bf(f.x); o.y = f2bf(f.y); o.z = f2bf(f.z); o.w = f2bf(f.w);
  *(ushort4*)(dp + gi) = o;
}

// ---------------- bias concat ----------------
__global__ __launch_bounds__(512) void biascat_k(
    const float* __restrict__ bkp, const float* __restrict__ bvp,
    const float* __restrict__ bqp, const float* __restrict__ bkd,
    const float* __restrict__ bvd, float* __restrict__ bp3,
    float* __restrict__ bd2) {
  int t = threadIdx.x;
  bp3[t] = bkp[t];
  bp3[512 + t] = bvp[t];
  bp3[1024 + t] = bqp[t];
  bd2[t] = bkd[t];
  bd2[512 + t] = bvd[t];
}

// ---------------- uncertainty gates ----------------
__device__ __forceinline__ float softplus_s(float x) {
  return fmaxf(x, 0.f) + log1pf(expf(-fabsf(x)));
}

__global__ __launch_bounds__(256) void gate_k(
    const float* __restrict__ hd, const float* __restrict__ hp,
    const float* __restrict__ wd, const float* __restrict__ bd,
    const float* __restrict__ wp, const float* __restrict__ bp,
    float* __restrict__ lgd, float* __restrict__ lgp, int mdTok) {
  const int lane = threadIdx.x & 63, wv = threadIdx.x >> 6;
  size_t tok = (size_t)blockIdx.x * 4 + wv;
  const float* h; const float* w4; const float* b4; float* lg;
  if (tok < (size_t)mdTok) { h = hd; w4 = wd; b4 = bd; lg = lgd; }
  else { h = hp; w4 = wp; b4 = bp; lg = lgp; tok -= mdTok; }
  const float* x = h + tok * 512;
  float s0 = 0.f, s1 = 0.f, s2 = 0.f, s3 = 0.f;
  #pragma unroll
  for (int i = 0; i < 8; ++i) {
    int c = (i << 6) + lane;
    float xv = x[c];
    s0 += xv * w4[c];
    s1 += xv * w4[512 + c];
    s2 += xv * w4[1024 + c];
    s3 += xv * w4[1536 + c];
  }
  s0 = wred_sum(s0); s1 = wred_sum(s1); s2 = wred_sum(s2); s3 = wred_sum(s3);
  if (lane == 0) {
    float mu = s0 + b4[0];
    float va = softplus_s(s1 + b4[1]) + 1e-6f;
    float al = softplus_s(s2 + b4[2]) + 1.f + 1e-6f;
    float be = softplus_s(s3 + b4[3]) + 1e-6f;
    float se2 = be / (va * (al - 1.f));
    float g = (1.f / (1.f + expf(-mu))) * expf(-se2);
    g = fminf(fmaxf(g, 1e-3f), 1.f);
    lg[tok] = logf(g + 1e-9f);
  }
}

// ---------------- residual(bf16) + LayerNorm ----------------
template <int OUT>
__global__ __launch_bounds__(256) void ln_k(const u16* __restrict__ res,
                                            const u16* __restrict__ y,
                                            const float* __restrict__ sc,
                                            const float* __restrict__ bi,
                                            void* __restrict__ outv) {
  const int lane = threadIdx.x & 63, w = threadIdx.x >> 6;
  const size_t row = (size_t)blockIdx.x * 4 + w;
  const int c0 = lane * 8;
  float v[8];
  s16x8 yv = *(const s16x8*)(y + row * 512 + c0);
  s16x8 rv = *(const s16x8*)(res + row * 512 + c0);
  float s = 0.f;
  #pragma unroll
  for (int i = 0; i < 8; ++i) {
    v[i] = bf2f((u16)rv[i]) + bf2f((u16)yv[i]);
    s += v[i];
  }
  s = wred_sum(s);
  float m = s * (1.f / 512.f);
  float s2 = 0.f;
  #pragma unroll
  for (int i = 0; i < 8; ++i) { float d = v[i] - m; s2 += d * d; }
  s2 = wred_sum(s2);
  float inv = rsqrtf(s2 * (1.f / 512.f) + 1e-5f);
  float4 sc0 = *(const float4*)(sc + c0), sc1 = *(const float4*)(sc + c0 + 4);
  float4 bi0 = *(const float4*)(bi + c0), bi1 = *(const float4*)(bi + c0 + 4);
  float scv[8] = {sc0.x, sc0.y, sc0.z, sc0.w, sc1.x, sc1.y, sc1.z, sc1.w};
  float biv[8] = {bi0.x, bi0.y, bi0.z, bi0.w, bi1.x, bi1.y, bi1.z, bi1.w};
  float o[8];
  #pragma unroll
  for (int i = 0; i < 8; ++i) o[i] = (v[i] - m) * inv * scv[i] + biv[i];
  if constexpr (OUT == 0) {
    float* of = (float*)outv + row * 512 + c0;
    *(float4*)of = float4{o[0], o[1], o[2], o[3]};
    *(float4*)(of + 4) = float4{o[4], o[5], o[6], o[7]};
  } else {
    s16x8 ov;
    #pragma unroll
    for (int i = 0; i < 8; ++i) ov[i] = (short)f2bf(o[i]);
    *(s16x8*)((u16*)outv + row * 512 + c0) = ov;
  }
}

// ---------------- fused flash cross-attention (Out may alias Q: per-block disjoint) ----------------
template <int KT>
__global__ __launch_bounds__(256) void flash_k(
    const u16* __restrict__ Q, const u16* __restrict__ Kv,
    const u16* __restrict__ Vt, const float* __restrict__ logg,
    const int* __restrict__ mask, u16* __restrict__ Out,
    int Lq, int Lk, float scale) {
  __shared__ __align__(16) u16 Kl[KT * 64];
  __shared__ __align__(16) u16 Vl[64 * KT];
  __shared__ __align__(16) u16 Pl[64 * (KT + 8)];
  const int tid = threadIdx.x;
  const int lane = tid & 63, wv = tid >> 6;
  const int lr = lane & 15, lg4 = lane >> 4;
  const int bh = blockIdx.z;
  const int b = bh >> 3, h = bh & 7;
  const int q0 = blockIdx.x * 64;

  bfrag af[2];
  {
    const u16* qrow = Q + (size_t)(b * Lq + q0 + wv * 16 + lr) * 512 + h * 64;
    af[0] = *(const bfrag*)(qrow + lg4 * 8);
    af[1] = *(const bfrag*)(qrow + 32 + lg4 * 8);
  }
  float mreg[4] = {-3e38f, -3e38f, -3e38f, -3e38f};
  float lreg[4] = {0.f, 0.f, 0.f, 0.f};
  f32x4 Oa[4] = {};
  const float* lgb = logg + (size_t)b * Lk;
  const int* mkb = mask + (size_t)b * Lk;

  const int NKT = Lk / KT;
  for (int t = 0; t < NKT; ++t) {
    const int k0 = t * KT;
    __syncthreads();
    {
      const char* kb = (const char*)(Kv + (size_t)(b * Lk + k0) * 512 + h * 64);
      #pragma unroll
      for (int r = 0; r < KT / 32; ++r) {
        int o = r * 4096 + tid * 16;
        int rr = o >> 7, cd = (o >> 4) & 7;
        int cs = cd ^ (rr & 7);
        g2l16(kb + (size_t)rr * 1024 + cs * 16, (char*)Kl + o);
      }
      const char* vb = (const char*)(Vt + (size_t)bh * 64 * Lk + k0);
      #pragma unroll
      for (int r = 0; r < KT / 32; ++r) {
        int o = r * 4096 + tid * 16;
        int rr = o >> 8, cd = (o >> 4) & 15;
        int cs = (cd & 8) | ((cd & 7) ^ (rr & 7));
        g2l16(vb + (size_t)rr * (Lk * 2) + cs * 16, (char*)Vl + o);
      }
    }
    __syncthreads();

    f32x4 sa[KT / 16];
    #pragma unroll
    for (int n = 0; n < KT / 16; ++n) {
      sa[n] = f32x4{0.f, 0.f, 0.f, 0.f};
      int row = n * 16 + lr;
      #pragma unroll
      for (int ks = 0; ks < 2; ++ks) {
        bfrag kf = *(const bfrag*)(Kl + row * 64 + (((ks * 4 + lg4) ^ (row & 7)) * 8));
        sa[n] = mfma16(af[ks], kf, sa[n]);
      }
    }
    asm volatile("s_nop 7\n\ts_nop 7");

    float pv[KT / 16][4];
    float nm[4] = {-3e38f, -3e38f, -3e38f, -3e38f};
    #pragma unroll
    for (int n = 0; n < KT / 16; ++n) {
      int kk = k0 + n * 16 + lr;
      float lgv = lgb[kk];
      int mkv = mkb[kk];
      #pragma unroll
      for (int e = 0; e < 4; ++e) {
        float tv = mkv ? fmaf(sa[n][e], scale, lgv) : -1e9f;
        pv[n][e] = tv;
        nm[e] = fmaxf(nm[e], tv);
      }
    }
    float fac[4], rs[4];
    #pragma unroll
    for (int e = 0; e < 4; ++e) {
      nm[e] = fmaxf(nm[e], __shfl_xor(nm[e], 1));
      nm[e] = fmaxf(nm[e], __shfl_xor(nm[e], 2));
      nm[e] = fmaxf(nm[e], __shfl_xor(nm[e], 4));
      nm[e] = fmaxf(nm[e], __shfl_xor(nm[e], 8));
      nm[e] = fmaxf(nm[e], mreg[e]);
      fac[e] = __expf(mreg[e] - nm[e]);
      mreg[e] = nm[e];
      rs[e] = 0.f;
    }
    #pragma unroll
    for (int n = 0; n < KT / 16; ++n)
      #pragma unroll
      for (int e = 0; e < 4; ++e) {
        float p = __expf(pv[n][e] - nm[e]);
        pv[n][e] = p;
        rs[e] += p;
      }
    #pragma unroll
    for (int e = 0; e < 4; ++e) {
      rs[e] += __shfl_xor(rs[e], 1);
      rs[e] += __shfl_xor(rs[e], 2);
      rs[e] += __shfl_xor(rs[e], 4);
      rs[e] += __shfl_xor(rs[e], 8);
      lreg[e] = lreg[e] * fac[e] + rs[e];
    }
    #pragma unroll
    for (int n2 = 0; n2 < 4; ++n2)
      #pragma unroll
      for (int e = 0; e < 4; ++e) Oa[n2][e] *= fac[e];

    {
      int prow = wv * 16 + lg4 * 4;
      #pragma unroll
      for (int n = 0; n < KT / 16; ++n)
        #pragma unroll
        for (int e = 0; e < 4; ++e)
          Pl[(prow + e) * (KT + 8) + n * 16 + lr] = f2bf(pv[n][e]);
    }
    #pragma unroll
    for (int ks = 0; ks < KT / 32; ++ks) {
      bfrag pf = *(const bfrag*)(Pl + (wv * 16 + lr) * (KT + 8) + (ks * 4 + lg4) * 8);
      #pragma unroll
      for (int n2 = 0; n2 < 4; ++n2) {
        int vrow = n2 * 16 + lr;
        int ch = ks * 4 + lg4;
        int chs = (ch & 8) | ((ch & 7) ^ (vrow & 7));
        bfrag vf = *(const bfrag*)(Vl + vrow * KT + chs * 8);
        Oa[n2] = mfma16(pf, vf, Oa[n2]);
      }
    }
  }
  asm volatile("s_nop 7\n\ts_nop 7");

  float inv[4];
  #pragma unroll
  for (int e = 0; e < 4; ++e) inv[e] = 1.f / lreg[e];
  u16* ob = Out + (size_t)(b * Lq + q0 + wv * 16 + lg4 * 4) * 512 + h * 64;
  #pragma unroll
  for (int n2 = 0; n2 < 4; ++n2)
    #pragma unroll
    for (int e = 0; e < 4; ++e)
      ob[(size_t)e * 512 + n2 * 16 + lr] = f2bf(Oa[n2][e] * inv[e]);
}

// ---------------- m97-structure 128x128 MFMA GEMM ----------------
// EPI: 1=bf16, 2=gelu->bf16,
//      4=kvq concat: c<512 -> C (ld 512); c<1024 -> V^T C2 (TR); else C3 (ld 512)
//      5=kd|vd concat: c<512 -> C; else V^T -> C2
template <int FM, int FN, int EPI>
__global__ __launch_bounds__(256) void gemm_k(
    const u16* __restrict__ A, const u16* __restrict__ W,
    const float* __restrict__ bias, void* __restrict__ C, void* __restrict__ C2,
    void* __restrict__ C3, int K, int lda, int ldw, int ldc, int NB, int TR) {
  constexpr int BM = 2 * FM * 16;
  constexpr int BN = 2 * FN * 16;
  __shared__ __align__(16) u16 Al[BM * 64];
  __shared__ __align__(16) u16 Wl[BN * 64];
  const int tid = threadIdx.x;
  const int qq = gridDim.x >> 3;
  const int wg = (blockIdx.x & 7) * qq + (blockIdx.x >> 3);
  const int bx = wg % NB, by = wg / NB;
  const int row0 = by * BM, col0 = bx * BN;
  const int lane = tid & 63, wv = tid >> 6;
  const int wr = wv >> 1, wc = wv & 1;
  const int rowW = wr * FM * 16, colW = wc * FN * 16;
  const int lr = lane & 15, lg4 = lane >> 4;

  const u16* aSrc[BM / 32];
  const u16* wSrc[BN / 32];
  int aDst[BM / 32], wDst[BN / 32];
  #pragma unroll
  for (int r = 0; r < BM / 32; ++r) {
    int o = r * 4096 + tid * 16;
    int arow = o >> 7, cd = (o >> 4) & 7, cs = cd ^ (arow & 7);
    aSrc[r] = A + (size_t)(row0 + arow) * lda + cs * 8;
    aDst[r] = o;
  }
  #pragma unroll
  for (int r = 0; r < BN / 32; ++r) {
    int o = r * 4096 + tid * 16;
    int wrow = o >> 7, cd = (o >> 4) & 7, cs = cd ^ (wrow & 7);
    wSrc[r] = W + (size_t)(col0 + wrow) * ldw + cs * 8;
    wDst[r] = o;
  }
  int aOff[FM][2], wOff[FN][2];
  #pragma unroll
  for (int m = 0; m < FM; ++m) {
    int rowi = rowW + m * 16 + lr;
    #pragma unroll
    for (int ks = 0; ks < 2; ++ks)
      aOff[m][ks] = rowi * 64 + (((ks * 4 + lg4) ^ (rowi & 7)) * 8);
  }
  #pragma unroll
  for (int n = 0; n < FN; ++n) {
    int rowi = colW + n * 16 + lr;
    #pragma unroll
    for (int ks = 0; ks < 2; ++ks)
      wOff[n][ks] = rowi * 64 + (((ks * 4 + lg4) ^ (rowi & 7)) * 8);
  }

  f32x4 acc[FM][FN] = {};

  for (int k0 = 0; k0 < K; k0 += 64) {
    #pragma unroll
    for (int r = 0; r < BM / 32; ++r) g2l16(aSrc[r] + k0, (char*)Al + aDst[r]);
    #pragma unroll
    for (int r = 0; r < BN / 32; ++r) g2l16(wSrc[r] + k0, (char*)Wl + wDst[r]);
    __syncthreads();
    #pragma unroll
    for (int ks = 0; ks < 2; ++ks) {
      bfrag af[FM], wf[FN];
      #pragma unroll
      for (int m = 0; m < FM; ++m) af[m] = *(const bfrag*)(Al + aOff[m][ks]);
      #pragma unroll
      for (int n = 0; n < FN; ++n) wf[n] = *(const bfrag*)(Wl + wOff[n][ks]);
      #pragma unroll
      for (int m = 0; m < FM; ++m)
        #pragma unroll
        for (int n = 0; n < FN; ++n) acc[m][n] = mfma16(af[m], wf[n], acc[m][n]);
    }
    if (k0 + 64 < K) __syncthreads();
  }
  asm volatile("s_nop 7\n\ts_nop 7\n\ts_nop 7");

  #pragma unroll
  for (int m = 0; m < FM; ++m) {
    #pragma unroll
    for (int n = 0; n < FN; ++n) {
      int rb = row0 + rowW + m * 16 + lg4 * 4;
      int c = col0 + colW + n * 16 + lr;
      float bv = bias[c];
      if constexpr (EPI == 1) {
        u16* Cu = (u16*)C;
        #pragma unroll
        for (int e = 0; e < 4; ++e)
          Cu[(size_t)(rb + e) * ldc + c] = f2bf(acc[m][n][e] + bv);
      } else if constexpr (EPI == 2) {
        u16* Cu = (u16*)C;
        #pragma unroll
        for (int e = 0; e < 4; ++e)
          Cu[(size_t)(rb + e) * ldc + c] = f2bf(gelu_f(acc[m][n][e] + bv));
      } else if constexpr (EPI == 4) {
        if (c < 512) {
          u16* Cu = (u16*)C;
          #pragma unroll
          for (int e = 0; e < 4; ++e)
            Cu[(size_t)(rb + e) * 512 + c] = f2bf(acc[m][n][e] + bv);
        } else if (c < 1024) {
          u16* Cu = (u16*)C2;
          int cl = c - 512;
          int b2 = rb / TR, j0 = rb - b2 * TR;
          int h2 = cl >> 6, dd = cl & 63;
          ushort4 pk;
          pk.x = f2bf(acc[m][n][0] + bv);
          pk.y = f2bf(acc[m][n][1] + bv);
          pk.z = f2bf(acc[m][n][2] + bv);
          pk.w = f2bf(acc[m][n][3] + bv);
          *(ushort4*)&Cu[(((size_t)b2 * 8 + h2) * 64 + dd) * TR + j0] = pk;
        } else {
          u16* Cu = (u16*)C3;
          int cl = c - 1024;
          #pragma unroll
          for (int e = 0; e < 4; ++e)
            Cu[(size_t)(rb + e) * 512 + cl] = f2bf(acc[m][n][e] + bv);
        }
      } else {  // EPI == 5
        if (c < 512) {
          u16* Cu = (u16*)C;
          #pragma unroll
          for (int e = 0; e < 4; ++e)
            Cu[(size_t)(rb + e) * ldc + c] = f2bf(acc[m][n][e] + bv);
        } else {
          u16* Cu = (u16*)C2;
          int cl = c - 512;
          int b2 = rb / TR, j0 = rb - b2 * TR;
          int h2 = cl >> 6, dd = cl & 63;
          ushort4 pk;
          pk.x = f2bf(acc[m][n][0] + bv);
          pk.y = f2bf(acc[m][n][1] + bv);
          pk.z = f2bf(acc[m][n][2] + bv);
          pk.w = f2bf(acc[m][n][3] + bv);
          *(ushort4*)&Cu[(((size_t)b2 * 8 + h2) * 64 + dd) * TR + j0] = pk;
        }
      }
    }
  }
}

// =============================== host ===============================
extern "C" void kernel_launch(void* const* d_in, const int* in_sizes, int n_in,
                              void* d_out, int out_size, void* d_ws, size_t ws_size,
                              hipStream_t stream) {
  const float* h_d = (const float*)d_in[0];
  const float* h_p = (const float*)d_in[1];
  const float* gd_w = (const float*)d_in[2];
  const float* gd_b = (const float*)d_in[3];
  const float* gp_w = (const float*)d_in[4];
  const float* gp_b = (const float*)d_in[5];
  const float* wqd_w = (const float*)d_in[6];  const float* wqd_b = (const float*)d_in[7];
  const float* wkp_w = (const float*)d_in[8];  const float* wkp_b = (const float*)d_in[9];
  const float* wvp_w = (const float*)d_in[10]; const float* wvp_b = (const float*)d_in[11];
  const float* wqp_w = (const float*)d_in[12]; const float* wqp_b = (const float*)d_in[13];
  const float* wkd_w = (const float*)d_in[14]; const float* wkd_b = (const float*)d_in[15];
  const float* wvd_w = (const float*)d_in[16]; const float* wvd_b = (const float*)d_in[17];
  const float* od_w = (const float*)d_in[18];  const float* od_b = (const float*)d_in[19];
  const float* op_w = (const float*)d_in[20];  const float* op_b = (const float*)d_in[21];
  const float* fd1_w = (const float*)d_in[22]; const float* fd1_b = (const float*)d_in[23];
  const float* fd2_w = (const float*)d_in[24]; const float* fd2_b = (const float*)d_in[25];
  const float* fp1_w = (const float*)d_in[26]; const float* fp1_b = (const float*)d_in[27];
  const float* fp2_w = (const float*)d_in[28]; const float* fp2_b = (const float*)d_in[29];
  const float* nd1_s = (const float*)d_in[30]; const float* nd1_b = (const float*)d_in[31];
  const float* nd2_s = (const float*)d_in[32]; const float* nd2_b = (const float*)d_in[33];
  const float* np1_s = (const float*)d_in[34]; const float* np1_b = (const float*)d_in[35];
  const float* np2_s = (const float*)d_in[36]; const float* np2_b = (const float*)d_in[37];
  const int* mask_d = (const int*)d_in[38];
  const int* mask_p = (const int*)d_in[39];

  constexpr int B = 16, Ld = 256, Lp = 1024, D = 512, H = 8, F = 2048;
  constexpr int Md = B * Ld;   // 4096
  constexpr int Mp = B * Lp;   // 16384
  constexpr int BH = B * H;    // 128

  char* ws = (char*)d_ws;
  size_t off = 0;
  auto alloc = [&](size_t bytes) {
    size_t o = off;
    off += (bytes + 255) & ~(size_t)255;
    return o;
  };
  auto a16 = [&](size_t els) { return (u16*)(ws + alloc(els * 2)); };
  auto a32 = [&](size_t els) { return (float*)(ws + alloc(els * 4)); };

  u16* w_qd = a16((size_t)D * D);
  u16* w_kp = a16((size_t)D * D);  // w_kp|w_vp|w_qp contiguous (1536 x 512)
  u16* w_vp = a16((size_t)D * D);
  u16* w_qp = a16((size_t)D * D);
  u16* w_kd = a16((size_t)D * D);  // w_kd|w_vd contiguous (1024 x 512)
  u16* w_vd = a16((size_t)D * D);
  u16* w_od = a16((size_t)D * D);
  u16* w_op = a16((size_t)D * D);
  u16* w_fd1 = a16((size_t)F * D);
  u16* w_fd2 = a16((size_t)F * D);
  u16* w_fp1 = a16((size_t)F * D);
  u16* w_fp2 = a16((size_t)F * D);

  u16* hd16 = a16((size_t)Md * D);     // h_d bf16 (pristine; LN1 residual)
  u16* hd2_16 = a16((size_t)Md * D);   // h_d'
  u16* hp16 = a16((size_t)Mp * D);     // h_p bf16 -> h_p' after LN2 (in-place)
  u16* qd16 = a16((size_t)Md * D);     // qd -> attn1 out (in-place) -> kd
  u16* kp16 = a16((size_t)Mp * D);     // kp
  u16* qp16 = a16((size_t)Mp * D);     // qp -> attn2 out (in-place)
  u16* vt16 = a16((size_t)Mp * D);     // vp^T -> vd^T
  u16* obuf16 = a16((size_t)Mp * D);   // o-proj / ffn2 outputs
  u16* t16 = a16((size_t)Mp * F);      // ffn hidden
  float* logg_d = a32(Md);
  float* logg_p = a32(Mp);
  float* bp3 = a32(1536);
  float* bd2 = a32(1024);

  // --- fused conversions ---
  {
    CvtArgs a;
    const float* src[14] = {h_d, h_p, wqd_w, wkp_w, wvp_w, wqp_w, wkd_w,
                            wvd_w, od_w, op_w, fd1_w, fd2_w, fp1_w, fp2_w};
    u16* dst[14] = {hd16, hp16, w_qd, w_kp, w_vp, w_qp, w_kd,
                    w_vd, w_od, w_op, w_fd1, w_fd2, w_fp1, w_fp2};
    const int nelem[14] = {Md * D, Mp * D, D * D, D * D, D * D, D * D, D * D,
                           D * D, D * D, D * D, F * D, F * D, F * D, F * D};
    int pfx = 0;
    for (int i = 0; i < 14; ++i) {
      a.s[i] = src[i];
      a.d[i] = dst[i];
      pfx += nelem[i] / 1024;
      a.eb[i] = pfx;
    }
    cvt_all<<<pfx, 256, 0, stream>>>(a);
  }
  biascat_k<<<1, 512, 0, stream>>>(wkp_b, wvp_b, wqp_b, wkd_b, wvd_b, bp3, bd2);

  // --- gates (ORIGINAL fp32 inputs) ---
  gate_k<<<(Md + Mp) / 4, 256, 0, stream>>>(h_d, h_p, gd_w, gd_b, gp_w, gp_b,
                                            logg_d, logg_p, Md);

  // --- fused kp|vp|qp projection (one launch, h_p read once) ---
  gemm_k<4, 4, 4><<<(Mp / 128) * (1536 / 128), 256, 0, stream>>>(
      hp16, w_kp, bp3, kp16, vt16, qp16, D, D, D, D, 1536 / 128, Lp);

  // --- qd projection ---
  gemm_k<4, 4, 1><<<(Md / 128) * (D / 128), 256, 0, stream>>>(
      hd16, w_qd, wqd_b, qd16, nullptr, nullptr, D, D, D, D, D / 128, 0);

  // --- attn1 (out in-place over qd16) ---
  flash_k<128><<<dim3(Ld / 64, 1, BH), 256, 0, stream>>>(
      qd16, kp16, vt16, logg_p, mask_p, qd16, Ld, Lp, 0.125f);

  // --- o-proj + LN1 -> h_d' ---
  gemm_k<4, 4, 1><<<(Md / 128) * (D / 128), 256, 0, stream>>>(
      qd16, w_od, od_b, obuf16, nullptr, nullptr, D, D, D, D, D / 128, 0);
  ln_k<1><<<Md / 4, 256, 0, stream>>>(hd16, obuf16, nd1_s, nd1_b, hd2_16);

  // --- kd|vd concat projection (from UPDATED drug) ---
  gemm_k<4, 4, 5><<<(Md / 128) * (1024 / 128), 256, 0, stream>>>(
      hd2_16, w_kd, bd2, qd16, vt16, nullptr, D, D, D, D, 1024 / 128, Ld);

  // --- attn2 (out in-place over qp16) ---
  flash_k<128><<<dim3(Lp / 64, 1, BH), 256, 0, stream>>>(
      qp16, qd16, vt16, logg_d, mask_d, qp16, Lp, Ld, 0.125f);

  // --- o-proj + LN2 -> h_p' (in-place into hp16) ---
  gemm_k<4, 4, 1><<<(Mp / 128) * (D / 128), 256, 0, stream>>>(
      qp16, w_op, op_b, obuf16, nullptr, nullptr, D, D, D, D, D / 128, 0);
  ln_k<1><<<Mp / 4, 256, 0, stream>>>(hp16, obuf16, np1_s, np1_b, hp16);

  // --- FFN drug + final LN -> d_out[0 : Md*D] ---
  gemm_k<4, 4, 2><<<(Md / 128) * (F / 128), 256, 0, stream>>>(
      hd2_16, w_fd1, fd1_b, t16, nullptr, nullptr, D, D, D, F, F / 128, 0);
  gemm_k<4, 4, 1><<<(Md / 128) * (D / 128), 256, 0, stream>>>(
      t16, w_fd2, fd2_b, obuf16, nullptr, nullptr, F, F, F, D, D / 128, 0);
  ln_k<0><<<Md / 4, 256, 0, stream>>>(hd2_16, obuf16, nd2_s, nd2_b, (float*)d_out);

  // --- FFN protein + final LN -> d_out[Md*D : ] ---
  gemm_k<4, 4, 2><<<(Mp / 128) * (F / 128), 256, 0, stream>>>(
      hp16, w_fp1, fp1_b, t16, nullptr, nullptr, D, D, D, F, F / 128, 0);
  gemm_k<4, 4, 1><<<(Mp / 128) * (D / 128), 256, 0, stream>>>(
      t16, w_fp2, fp2_b, obuf16, nullptr, nullptr, F, F, F, D, D / 128, 0);
  ln_k<0><<<Mp / 4, 256, 0, stream>>>(hp16, obuf16, np2_s, np2_b,
                                      (float*)d_out + (size_t)Md * D);
}